// Round 5
// baseline (235.930 us; speedup 1.0000x reference)
//
#include <hip/hip_runtime.h>
#include <stdint.h>

typedef unsigned int u32;
typedef unsigned short u16;

#define N_  1024
#define F_  512
#define ALPHA 0.2f
#define TSTR 68   // k_prep LDS tile stride (u16)

typedef __attribute__((ext_vector_type(8))) short short8;
typedef __attribute__((ext_vector_type(4))) float float4v;

union Frag { short8 s; u32 u[4]; };

static __device__ __forceinline__ float bits2f(u32 b){ union{u32 u; float f;} c; c.u=b; return c.f; }
static __device__ __forceinline__ u32   f2bits(float f){ union{float f_; u32 u;} c; c.f_=f; return c.u; }
static __device__ __forceinline__ float bflo(u32 p){ return bits2f(p<<16); }
static __device__ __forceinline__ float bfhi(u32 p){ return bits2f(p & 0xffff0000u); }
static __device__ __forceinline__ u32   f2bf(float f){ u32 u=f2bits(f); return (u + 0x7fffu + ((u>>16)&1u))>>16; }

// async global->LDS, 16 B per lane; LDS dest = wave-uniform base + lane*16
static __device__ __forceinline__ void gload_lds16(const void* g, void* l){
    __builtin_amdgcn_global_load_lds((const __attribute__((address_space(1))) u32*)g,
                                     (__attribute__((address_space(3))) u32*)l, 16, 0, 0);
}

// ---- kernel 1: fused (W^T a) slice + transpose X->XT bf16 + row-dot atomics ----
// grid (16 m-tiles, 8 f-slices, 16 b), 256 thr.
__global__ __launch_bounds__(256)
void k_prep(const float* __restrict__ X, const float* __restrict__ W,
            const float* __restrict__ a1, const float* __restrict__ a2,
            u16* __restrict__ XT, float* __restrict__ d1acc, float* __restrict__ d2acc){
    __shared__ u16 tile[64*TSTR];
    __shared__ float wred[8][64];
    __shared__ float w1s[64], w2s[64];
    const int t  = threadIdx.x;
    const int m0 = blockIdx.x*64, f0 = blockIdx.y*64, b = blockIdx.z;

    // --- phase A: w1s[f] = sum_o W[o][f0+f]*a1[o], same for a2 (redundant per block, L2-hit) ---
    {
        const int fl = t & 63, oc = t >> 6;     // 4 o-chunks of 128
        float s1 = 0.f, s2 = 0.f;
        const float* Wp = W + f0 + fl;
        #pragma unroll 8
        for(int o = oc*128; o < oc*128 + 128; o++){
            float w = Wp[o*F_];
            s1 += w * a1[o];
            s2 += w * a2[o];
        }
        wred[oc][fl] = s1; wred[4+oc][fl] = s2;
    }
    __syncthreads();
    if(t < 64)            w1s[t]    = wred[0][t]   + wred[1][t]   + wred[2][t]   + wred[3][t];
    else if(t < 128){ int f = t-64; w2s[f] = wred[4][f] + wred[5][f] + wred[6][f] + wred[7][f]; }
    __syncthreads();

    // --- phase B: 64x64 tile transpose + per-row partial dots ---
    const int ml = t>>4, fl4 = (t&15)*4;
    float4 w1q = *(const float4*)(w1s + fl4);
    float4 w2q = *(const float4*)(w2s + fl4);
    float d1p[4], d2p[4];
    #pragma unroll
    for(int rr=0;rr<4;rr++){
        int m = ml + rr*16;
        float4 v = *(const float4*)(X + ((size_t)(b*N_ + m0 + m))*F_ + f0 + fl4);
        tile[(fl4+0)*TSTR + m] = (u16)f2bf(v.x);
        tile[(fl4+1)*TSTR + m] = (u16)f2bf(v.y);
        tile[(fl4+2)*TSTR + m] = (u16)f2bf(v.z);
        tile[(fl4+3)*TSTR + m] = (u16)f2bf(v.w);
        d1p[rr] = v.x*w1q.x + v.y*w1q.y + v.z*w1q.z + v.w*w1q.w;
        d2p[rr] = v.x*w2q.x + v.y*w2q.y + v.z*w2q.z + v.w*w2q.w;
    }
    #pragma unroll
    for(int s=1;s<16;s<<=1){
        #pragma unroll
        for(int rr=0;rr<4;rr++){ d1p[rr] += __shfl_xor(d1p[rr],s,64); d2p[rr] += __shfl_xor(d2p[rr],s,64); }
    }
    if((t&15)==0){
        #pragma unroll
        for(int rr=0;rr<4;rr++){
            atomicAdd(&d1acc[b*N_ + m0 + ml + rr*16], d1p[rr]);
            atomicAdd(&d2acc[b*N_ + m0 + ml + rr*16], d2p[rr]);
        }
    }
    __syncthreads();
    const int fl = t>>4, ml4 = (t&15)*4;
    #pragma unroll
    for(int rr=0;rr<4;rr++){
        int f = fl + rr*16;
        uint2 val = *(const uint2*)(&tile[f*TSTR + ml4]);
        *(uint2*)(XT + ((size_t)(b*F_ + f0 + f))*N_ + m0 + ml4) = val;
    }
}

// ---- kernel 2: fused exp-tables + scores + softmax + PV + ELU ----
// grid (32, 16): gx -> n-tile (gx&15), f-half (gx>>4; stride 16 = same XCD as partner); gy = b.
// block 256 = 4 waves (nsub 0..3); wave: 16 n-rows x 256 f; m-chunks of 32, dbuf async staging.
__global__ __launch_bounds__(256, 2)
void k_main(const u16* __restrict__ XT, const int* __restrict__ adj,
            const float* __restrict__ d1acc, const float* __restrict__ d2acc,
            float* __restrict__ out){
    __shared__ u16 xbuf[2][8192];      // [dbuf][16 ct * 512 u16], 32 KB
    __shared__ u32 lds_e2[N_];         // packed bf16(exp(f2)),bf16(exp(.2 f2)) per m-row, 4 KB
    __shared__ float e1p_s[64], e1n_s[64];

    const int t    = threadIdx.x;
    const int lane = t & 63;
    const int wv   = t >> 6;           // 0..3
    const int nsub = wv;
    const int gx   = blockIdx.x;
    const int fh   = gx >> 4;
    const int n0   = (gx & 15) * 64;
    const int b    = blockIdx.y;
    const int r16  = lane & 15;
    const int quad = lane >> 4;
    const int nrow = n0 + nsub*16 + r16;

    const u16* XTb = XT + (size_t)b*F_*N_ + (size_t)(fh*256)*N_;

    // stage chunk 0 -> buf 0 (16 calls over 4 waves; lane covers f=c*16+r16, m=quad*8)
    #pragma unroll
    for(int k=0;k<4;k++){
        int c = wv*4 + k;
        gload_lds16(XTb + (size_t)(c*16 + r16)*N_ + quad*8, &xbuf[0][c*512]);
    }

    // prologue: exp tables from d1/d2 sums
    {
        int r0 = t*4;
        float4 p1 = *(const float4*)(d1acc + (b<<10) + r0);
        float4 p2 = *(const float4*)(d2acc + (b<<10) + r0);
        uint4 pk;
        u32* pkp = (u32*)&pk;
        float d2a[4] = {p2.x, p2.y, p2.z, p2.w};
        #pragma unroll
        for(int j=0;j<4;j++){
            u32 lo = f2bf(__expf(d2a[j]));
            u32 hi = f2bf(__expf(ALPHA*d2a[j]));
            pkp[j] = lo | (hi<<16);
        }
        *(uint4*)(&lds_e2[r0]) = pk;
        float d1a[4] = {p1.x, p1.y, p1.z, p1.w};
        #pragma unroll
        for(int j=0;j<4;j++){
            int rr = r0 + j;
            if(rr >= n0 && rr < n0 + 64){
                e1p_s[rr - n0] = __expf(d1a[j]);
                e1n_s[rr - n0] = __expf(ALPHA*d1a[j]);
            }
        }
    }

    float4v acc[16];
    #pragma unroll
    for(int i=0;i<16;i++) acc[i] = (float4v){0.f,0.f,0.f,0.f};
    float dsum = 0.f;

    const int* adjRow = adj + ((size_t)(b*N_ + nrow))*N_ + quad*8;
    int adA[8], adB[8];
    *(int4*)(adA)   = *(const int4*)(adjRow);
    *(int4*)(adA+4) = *(const int4*)(adjRow + 4);
    *(int4*)(adB)   = *(const int4*)(adjRow + 32);
    *(int4*)(adB+4) = *(const int4*)(adjRow + 36);

    float e1pR = 0.f, e1nR = 0.f;
    int db = 0;
    for(int i=0;i<32;i++){
        const int m0 = i*32;
        __syncthreads();               // drains staging for xbuf[db]; i=0 also publishes exp tables
        if(i == 0){ e1pR = e1p_s[nsub*16 + r16]; e1nR = e1n_s[nsub*16 + r16]; }
        if(i < 31){
            const int ms = m0 + 32;
            #pragma unroll
            for(int k=0;k<4;k++){
                int c = wv*4 + k;
                gload_lds16(XTb + (size_t)(c*16 + r16)*N_ + ms + quad*8, &xbuf[db^1][c*512]);
            }
        }
        int pf = (i < 30) ? (m0 + 64) : 0;
        int adC[8];
        *(int4*)(adC)   = *(const int4*)(adjRow + pf);
        *(int4*)(adC+4) = *(const int4*)(adjRow + pf + 4);

        u32 ev[8];
        *(uint4*)(ev)   = *(const uint4*)(&lds_e2[m0 + quad*8]);
        *(uint4*)(ev+4) = *(const uint4*)(&lds_e2[m0 + quad*8 + 4]);

        u32 pb[8];
        #pragma unroll
        for(int j=0;j<8;j++){
            float pp = e1pR * bflo(ev[j]);   // exp(f1)*exp(f2)     = exp(s)
            float pn = e1nR * bfhi(ev[j]);   // exp(.2f1)*exp(.2f2) = exp(.2s)
            float p  = (pp > 1.0f) ? pp : pn;          // lrelu: s>0 <=> exp(s)>1
            p = (adA[j] != 0) ? p : 0.0f;
            dsum += p;
            pb[j] = f2bf(p);
        }
        Frag af;
        af.u[0] = pb[0] | (pb[1]<<16);
        af.u[1] = pb[2] | (pb[3]<<16);
        af.u[2] = pb[4] | (pb[5]<<16);
        af.u[3] = pb[6] | (pb[7]<<16);

        const u16* bb = &xbuf[db][lane*8];   // lane-linear: conflict-free ds_read_b128
        #pragma unroll
        for(int ct=0; ct<16; ct++){
            uint4 bw = *(const uint4*)(bb + ct*512);
            Frag bf_;
            bf_.u[0]=bw.x; bf_.u[1]=bw.y; bf_.u[2]=bw.z; bf_.u[3]=bw.w;
            acc[ct] = __builtin_amdgcn_mfma_f32_16x16x32_bf16(af.s, bf_.s, acc[ct], 0, 0, 0);
        }
        #pragma unroll
        for(int j=0;j<8;j++){ adA[j] = adB[j]; adB[j] = adC[j]; }
        db ^= 1;
    }

    // ---- softmax denominator: reduce over quads in-wave, broadcast to C-layout rows ----
    dsum += __shfl_xor(dsum, 16, 64);
    dsum += __shfl_xor(dsum, 32, 64);
    float invr[4];
    #pragma unroll
    for(int r=0;r<4;r++){
        float dr = __shfl(dsum, quad*4 + r, 64);
        invr[r] = 1.0f / fmaxf(dr, 1e-30f);
    }
    // ---- epilogue: scale, ELU, fp32 store ----
    #pragma unroll
    for(int ct=0; ct<16; ct++){
        #pragma unroll
        for(int r=0;r<4;r++){
            float v = acc[ct][r] * invr[r];
            v = (v > 0.f) ? v : (__expf(v) - 1.f);
            int n_out = n0 + nsub*16 + quad*4 + r;
            out[((size_t)(b*N_ + n_out))*F_ + fh*256 + ct*16 + r16] = v;
        }
    }
}

extern "C" void kernel_launch(void* const* d_in, const int* in_sizes, int n_in,
                              void* d_out, int out_size, void* d_ws, size_t ws_size,
                              hipStream_t stream) {
    const float* X  = (const float*)d_in[0];   // [16,1024,512] fp32
    const int* adj  = (const int*)d_in[1];     // [16,1024,1024] int32
    const float* W  = (const float*)d_in[2];   // [512,512] fp32
    const float* a1 = (const float*)d_in[3];   // [512]
    const float* a2 = (const float*)d_in[4];   // [512]
    float* out = (float*)d_out;                // [16,1024,512] fp32

    float* ws    = (float*)d_ws;
    float* d1acc = ws;                          // [16][1024]
    float* d2acc = ws + 16384;                  // [16][1024]
    u16*  XT     = (u16*)(ws + 32768);          // 16.78 MB bf16 [b][f][m]

    hipMemsetAsync(d1acc, 0, 32768*sizeof(float), stream);
    k_prep<<<dim3(16, 8, 16), 256, 0, stream>>>(X, W, a1, a2, XT, d1acc, d2acc);
    k_main<<<dim3(32, 16), 256, 0, stream>>>(XT, adj, d1acc, d2acc, out);
}

// Round 7
// 217.652 us; speedup vs baseline: 1.0840x; 1.0840x over previous
//
#include <hip/hip_runtime.h>
#include <stdint.h>

typedef unsigned int u32;
typedef unsigned short u16;

#define N_  1024
#define F_  512
#define ALPHA 0.2f
#define TSTR 68   // k_prep LDS tile stride (u16)

typedef __attribute__((ext_vector_type(8))) short short8;
typedef __attribute__((ext_vector_type(4))) float float4v;

union Frag { short8 s; u32 u[4]; };

static __device__ __forceinline__ float bits2f(u32 b){ union{u32 u; float f;} c; c.u=b; return c.f; }
static __device__ __forceinline__ u32   f2bits(float f){ union{float f_; u32 u;} c; c.f_=f; return c.u; }
static __device__ __forceinline__ float bflo(u32 p){ return bits2f(p<<16); }
static __device__ __forceinline__ float bfhi(u32 p){ return bits2f(p & 0xffff0000u); }
static __device__ __forceinline__ u32   f2bf(float f){ u32 u=f2bits(f); return (u + 0x7fffu + ((u>>16)&1u))>>16; }

// ---- kernel 1: w12[0..512)=W^T a1, w12[512..1024)=W^T a2 (direct store, no atomics) ----
__global__ __launch_bounds__(256)
void k_w12(const float* __restrict__ W, const float* __restrict__ a1,
           const float* __restrict__ a2, float* __restrict__ w12){
    __shared__ float red[8][64];
    const int t = threadIdx.x;
    const int f0 = blockIdx.x*64;
    const int fl = t & 63, oc = t >> 6;          // 4 o-chunks of 128
    float s1 = 0.f, s2 = 0.f;
    const float* Wp = W + f0 + fl;
    #pragma unroll 8
    for(int o = oc*128; o < oc*128 + 128; o++){
        float w = Wp[(size_t)o*F_];
        s1 += w * a1[o];
        s2 += w * a2[o];
    }
    red[oc][fl] = s1; red[4+oc][fl] = s2;
    __syncthreads();
    if(t < 64)       w12[f0+t]            = red[0][t]+red[1][t]+red[2][t]+red[3][t];
    else if(t < 128){ int f=t-64; w12[512+f0+f] = red[4][f]+red[5][f]+red[6][f]+red[7][f]; }
}

// ---- kernel 2: transpose X->XT bf16 + full row dots d1,d2 (in-block f-loop, direct store) ----
// grid (16 m-tiles, 16 b) x 256 thr
__global__ __launch_bounds__(256)
void k_prep(const float* __restrict__ X, const float* __restrict__ w12,
            u16* __restrict__ XT, float* __restrict__ d12){
    __shared__ u16 tile[64*TSTR];
    const int t  = threadIdx.x;
    const int m0 = blockIdx.x*64, b = blockIdx.y;
    const int ml = t>>4, fl4 = (t&15)*4;   // loader mapping
    const int fl = t>>4, ml4 = (t&15)*4;   // storer mapping
    float d1p[4] = {0,0,0,0}, d2p[4] = {0,0,0,0};

    for(int ft=0; ft<8; ft++){
        const int f0 = ft*64;
        float4 w1q = *(const float4*)(w12 + f0 + fl4);
        float4 w2q = *(const float4*)(w12 + 512 + f0 + fl4);
        #pragma unroll
        for(int rr=0;rr<4;rr++){
            int m = ml + rr*16;
            float4 v = *(const float4*)(X + ((size_t)(b*N_ + m0 + m))*F_ + f0 + fl4);
            tile[(fl4+0)*TSTR + m] = (u16)f2bf(v.x);
            tile[(fl4+1)*TSTR + m] = (u16)f2bf(v.y);
            tile[(fl4+2)*TSTR + m] = (u16)f2bf(v.z);
            tile[(fl4+3)*TSTR + m] = (u16)f2bf(v.w);
            d1p[rr] += v.x*w1q.x + v.y*w1q.y + v.z*w1q.z + v.w*w1q.w;
            d2p[rr] += v.x*w2q.x + v.y*w2q.y + v.z*w2q.z + v.w*w2q.w;
        }
        __syncthreads();
        #pragma unroll
        for(int rr=0;rr<4;rr++){
            int f = fl + rr*16;
            uint2 val = *(const uint2*)(&tile[f*TSTR + ml4]);
            *(uint2*)(XT + ((size_t)(b*F_ + f0 + f))*N_ + m0 + ml4) = val;
        }
        __syncthreads();
    }
    // reduce partial dots over the 16 f-lanes (lane bits 0..3)
    #pragma unroll
    for(int s=1;s<16;s<<=1){
        #pragma unroll
        for(int rr=0;rr<4;rr++){ d1p[rr] += __shfl_xor(d1p[rr],s,64); d2p[rr] += __shfl_xor(d2p[rr],s,64); }
    }
    if((t&15)==0){
        #pragma unroll
        for(int rr=0;rr<4;rr++){
            int r = b*N_ + m0 + ml + rr*16;
            d12[r]         = d1p[rr];
            d12[16384 + r] = d2p[rr];
        }
    }
}

// ---- kernel 3: compress adj int32 -> bitmask u32[b][n][32] ----
__global__ __launch_bounds__(256)
void k_adj(const int* __restrict__ adj, u32* __restrict__ bits){
    const int t   = threadIdx.x;
    const int row = blockIdx.x*16 + (t>>4);
    const int b   = blockIdx.y;
    const int wi0 = (t&15)*2;
    const int* ap = adj + ((size_t)(b*N_) + row)*N_ + wi0*32;
    u32 mw[2] = {0,0};
    #pragma unroll
    for(int w=0;w<2;w++){
        #pragma unroll
        for(int k=0;k<8;k++){
            int4 v = *(const int4*)(ap + w*32 + k*4);
            mw[w] |= ((v.x!=0)?1u:0u)<<(k*4)
                   | ((v.y!=0)?1u:0u)<<(k*4+1)
                   | ((v.z!=0)?1u:0u)<<(k*4+2)
                   | ((v.w!=0)?1u:0u)<<(k*4+3);
        }
    }
    uint2 st; st.x = mw[0]; st.y = mw[1];
    *(uint2*)(bits + ((size_t)(b*N_) + row)*32 + wi0) = st;
}

// ---- kernel 4: fused scores+softmax+PV+ELU, barrier-free K-loop, register-pipelined B ----
// grid (16 n-tiles, 16 b) x 512 thr = 8 waves; wave = f-slab of 64 (wv), all 4 n-subtiles.
template<bool BITS>
__global__ __launch_bounds__(512, 2)
void k_main(const u16* __restrict__ XT, const u32* __restrict__ bits,
            const int* __restrict__ adj, const float* __restrict__ d12,
            float* __restrict__ out){
    __shared__ u32 e2[N_];   // packed bf16(exp(f2)) | bf16(exp(.2 f2)) per m-row

    const int t    = threadIdx.x;
    const int lane = t & 63;
    const int wv   = t >> 6;           // f-slab 0..7
    const int b    = blockIdx.y;
    const int n0   = blockIdx.x * 64;
    const int r16  = lane & 15;
    const int quad = lane >> 4;

    // prologue: e2 table (512 threads x 2 rows)
    {
        const float* d2p = d12 + 16384 + b*N_;
        float2 dv = *(const float2*)(d2p + t*2);
        u32 lo0 = f2bf(__expf(dv.x)), hi0 = f2bf(__expf(ALPHA*dv.x));
        u32 lo1 = f2bf(__expf(dv.y)), hi1 = f2bf(__expf(ALPHA*dv.y));
        e2[t*2]   = lo0 | (hi0<<16);
        e2[t*2+1] = lo1 | (hi1<<16);
    }
    float e1pR[4], e1nR[4];
    #pragma unroll
    for(int ns=0;ns<4;ns++){
        float d1 = d12[b*N_ + n0 + ns*16 + r16];
        e1pR[ns] = __expf(d1);
        e1nR[ns] = __expf(ALPHA*d1);
    }
    const u16* Bp   = XT + ((size_t)b*F_ + wv*64)*N_;       // wave's f-slab [64 f][1024 m]
    const u32* bitp = bits + ((size_t)(b*N_) + n0)*32;      // [64 rows][32 words]
    const int* adjp = adj + ((size_t)(b*N_) + n0)*N_;       // fallback source
    __syncthreads();   // e2 ready; no barriers after this until epilogue

    float4v acc[4][4];   // [ns][ct]
    #pragma unroll
    for(int i=0;i<4;i++)
        #pragma unroll
        for(int j=0;j<4;j++) acc[i][j] = (float4v){0.f,0.f,0.f,0.f};
    float dsum[4] = {0.f,0.f,0.f,0.f};

    // register pipeline: B-frags 2 chunks deep, mask words 1 deep
    uint4 Bcur[4], Bnext[4], Bnxt2[4];
    u32 bwc[4], bwn[4];
    int adA[4][8];
    #pragma unroll
    for(int ct=0;ct<4;ct++) Bcur[ct]  = *(const uint4*)(Bp + (size_t)(ct*16+r16)*N_ + quad*8);
    #pragma unroll
    for(int ct=0;ct<4;ct++) Bnext[ct] = *(const uint4*)(Bp + (size_t)(ct*16+r16)*N_ + 32 + quad*8);
    if(BITS){
        #pragma unroll
        for(int ns=0;ns<4;ns++) bwc[ns] = bitp[(ns*16+r16)*32];
    } else {
        #pragma unroll
        for(int ns=0;ns<4;ns++){
            const int* ap = adjp + (size_t)(ns*16+r16)*N_ + quad*8;
            *(int4*)(adA[ns])   = *(const int4*)(ap);
            *(int4*)(adA[ns]+4) = *(const int4*)(ap + 4);
        }
    }

    for(int i=0;i<32;i++){
        const int m0 = i*32;
        const int mL = (i<30) ? m0+64 : 0;     // tail wrap: loaded but never consumed
        #pragma unroll
        for(int ct=0;ct<4;ct++) Bnxt2[ct] = *(const uint4*)(Bp + (size_t)(ct*16+r16)*N_ + mL + quad*8);
        const int mN = (i<31) ? m0+32 : 0;
        int adB[4][8];
        if(BITS){
            #pragma unroll
            for(int ns=0;ns<4;ns++) bwn[ns] = bitp[(ns*16+r16)*32 + (mN>>5)];
        } else {
            #pragma unroll
            for(int ns=0;ns<4;ns++){
                const int* ap = adjp + (size_t)(ns*16+r16)*N_ + mN + quad*8;
                *(int4*)(adB[ns])   = *(const int4*)(ap);
                *(int4*)(adB[ns]+4) = *(const int4*)(ap + 4);
            }
        }

        u32 ev[8];
        *(uint4*)(ev)   = *(const uint4*)(&e2[m0 + quad*8]);      // broadcast, conflict-free
        *(uint4*)(ev+4) = *(const uint4*)(&e2[m0 + quad*8 + 4]);

        #pragma unroll
        for(int ns=0;ns<4;ns++){
            u32 pb[8];
            float ds = dsum[ns];
            #pragma unroll
            for(int j=0;j<8;j++){
                float pp = e1pR[ns] * bflo(ev[j]);   // exp(s)
                float pn = e1nR[ns] * bfhi(ev[j]);   // exp(0.2 s)
                float p  = fmaxf(pp, pn);            // == exp(lrelu(s)) exactly
                bool on = BITS ? (((bwc[ns] >> (quad*8 + j)) & 1u) != 0u) : (adA[ns][j] != 0);
                p = on ? p : 0.0f;
                ds += p;
                pb[j] = f2bf(p);
            }
            dsum[ns] = ds;
            Frag af;
            af.u[0] = pb[0] | (pb[1]<<16);
            af.u[1] = pb[2] | (pb[3]<<16);
            af.u[2] = pb[4] | (pb[5]<<16);
            af.u[3] = pb[6] | (pb[7]<<16);
            #pragma unroll
            for(int ct=0;ct<4;ct++){
                Frag bf_;
                bf_.u[0]=Bcur[ct].x; bf_.u[1]=Bcur[ct].y; bf_.u[2]=Bcur[ct].z; bf_.u[3]=Bcur[ct].w;
                acc[ns][ct] = __builtin_amdgcn_mfma_f32_16x16x32_bf16(af.s, bf_.s, acc[ns][ct], 0, 0, 0);
            }
        }
        #pragma unroll
        for(int ct=0;ct<4;ct++){ Bcur[ct] = Bnext[ct]; Bnext[ct] = Bnxt2[ct]; }
        if(BITS){
            #pragma unroll
            for(int ns=0;ns<4;ns++) bwc[ns] = bwn[ns];
        } else {
            #pragma unroll
            for(int ns=0;ns<4;ns++)
                #pragma unroll
                for(int j=0;j<8;j++) adA[ns][j] = adB[ns][j];
        }
    }

    // softmax denominators: reduce over quads (k-dim), broadcast to C-layout rows
    #pragma unroll
    for(int ns=0;ns<4;ns++){
        dsum[ns] += __shfl_xor(dsum[ns], 16, 64);
        dsum[ns] += __shfl_xor(dsum[ns], 32, 64);
    }
    float invr[4][4];
    #pragma unroll
    for(int ns=0;ns<4;ns++)
        #pragma unroll
        for(int r=0;r<4;r++){
            float dr = __shfl(dsum[ns], quad*4 + r, 64);
            invr[ns][r] = 1.0f / fmaxf(dr, 1e-30f);
        }
    // epilogue: scale, ELU, fp32 store
    #pragma unroll
    for(int ns=0;ns<4;ns++)
        #pragma unroll
        for(int ct=0;ct<4;ct++)
            #pragma unroll
            for(int r=0;r<4;r++){
                float v = acc[ns][ct][r] * invr[ns][r];
                v = (v > 0.f) ? v : (__expf(v) - 1.f);
                int n_out = n0 + ns*16 + quad*4 + r;
                out[((size_t)(b*N_ + n_out))*F_ + wv*64 + ct*16 + r16] = v;
            }
}

extern "C" void kernel_launch(void* const* d_in, const int* in_sizes, int n_in,
                              void* d_out, int out_size, void* d_ws, size_t ws_size,
                              hipStream_t stream) {
    const float* X  = (const float*)d_in[0];   // [16,1024,512] fp32
    const int* adj  = (const int*)d_in[1];     // [16,1024,1024] int32
    const float* W  = (const float*)d_in[2];   // [512,512] fp32
    const float* a1 = (const float*)d_in[3];   // [512]
    const float* a2 = (const float*)d_in[4];   // [512]
    float* out = (float*)d_out;                // [16,1024,512] fp32

    float* ws  = (float*)d_ws;
    float* w12 = ws;                            // [1024]
    float* d12 = ws + 1024;                     // d1 [16*1024] then d2 [16*1024]
    u32*  bits = (u32*)(ws + 33792);            // [16][1024][32] u32 = 2 MB -> ends at float 558080

    // primary layout: XT after bits (needs 19.01 MB); fallback: XT right after d12, no bits
    const size_t needBits = (size_t)558080*4 + (size_t)16*F_*N_*2;   // 19,009,536 B
    const bool useBits = (ws_size >= needBits);
    u16* XT = useBits ? (u16*)(ws + 558080) : (u16*)(ws + 33792);

    k_w12 <<<8,           256, 0, stream>>>(W, a1, a2, w12);
    if(useBits) k_adj<<<dim3(64,16), 256, 0, stream>>>(adj, bits);
    k_prep<<<dim3(16,16), 256, 0, stream>>>(X, w12, XT, d12);
    if(useBits) k_main<true> <<<dim3(16,16), 512, 0, stream>>>(XT, bits, adj, d12, out);
    else        k_main<false><<<dim3(16,16), 512, 0, stream>>>(XT, bits, adj, d12, out);
}